// Round 4
// baseline (784.620 us; speedup 1.0000x reference)
//
#include <hip/hip_runtime.h>

// Causal self-attention. Inputs fp32 (per reference dtype), output fp32.
// Internally: convert to bf16 once, MFMA 16x16x32 bf16 with fp32 accumulation.
// R4 root-cause fix: rounds 1-3 read the fp32 input buffers as bf16 (NaN via
// garbage exponent patterns). Now: cvt kernels fp32->bf16; fp32 epilogue.
// MFMA 16x16x32 bf16 layouts (guide m89/m91):
//   A[m=lane&15][k=quad*8+j], B[k=quad*8+j][n=lane&15], C/D: row=quad*4+r, col=lane&15

typedef unsigned short ushort;
typedef __attribute__((ext_vector_type(8))) short short8;
typedef __attribute__((ext_vector_type(4))) float floatx4;

#define T_SEQ 2048
#define NQKV  6144
#define DMODEL 2048
#define HDIM  128
#define NEG_BIG (-3.0e38f)

__device__ __forceinline__ ushort f2bf(float f) {
  unsigned u = __float_as_uint(f);
  u += 0x7fffu + ((u >> 16) & 1u);   // RNE
  return (ushort)(u >> 16);
}

__device__ __forceinline__ void stout(ushort* p, float v) { *p = f2bf(v); }
__device__ __forceinline__ void stout(float* p, float v)  { *p = v; }

// ---- fp32 [R x C slice of row-stride ld_in] -> dense bf16 [R x C] ----
__global__ void cvt2d(const float* __restrict__ in, ushort* __restrict__ out,
                      int R, int C, int ld_in) {
  int idx = blockIdx.x * blockDim.x + threadIdx.x;  // one thread per 4 elems
  int c4 = C >> 2;
  if (idx >= R * c4) return;
  int r = idx / c4, c = (idx - r * c4) * 4;
  float4 v = *(const float4*)(in + (size_t)r * ld_in + c);
  ushort4 o;
  o.x = f2bf(v.x); o.y = f2bf(v.y); o.z = f2bf(v.z); o.w = f2bf(v.w);
  *(ushort4*)(out + (size_t)r * C + c) = o;
}

// ---- C[M,N] = A[M,K] @ B[K,N], bf16 in, OutT out; C row stride ldc ----
// 128x128 tile, BK=32. sA[row][k] stride 40; sB[n][k] stride 40 (B transposed
// into LDS during staging so fragment reads are K-contiguous).
template <typename OutT>
__global__ __launch_bounds__(256, 2) void gemm_bn(
    const ushort* __restrict__ A, const ushort* __restrict__ B,
    OutT* __restrict__ C, int M, int N, int K, int ldc) {
  __shared__ ushort sA[128 * 40];
  __shared__ ushort sB[128 * 40];
  const int tid = threadIdx.x;
  const int w = tid >> 6, l = tid & 63;
  const int quad = l >> 4, l16 = l & 15;
  const int row0 = blockIdx.x * 128, col0 = blockIdx.y * 128;
  const int wm = (w >> 1) * 64, wn = (w & 1) * 64;

  floatx4 acc[4][4];
  const floatx4 zero = {0.f, 0.f, 0.f, 0.f};
#pragma unroll
  for (int i = 0; i < 4; i++)
#pragma unroll
    for (int j = 0; j < 4; j++) acc[i][j] = zero;

  const int ar = tid >> 2;          // A staging: rows {ar, 64+ar}, cols ac..+7
  const int ac = (tid & 3) * 8;
  const int bk = tid >> 3;          // B staging: k=bk, n=bn0..+15
  const int bn0 = (tid & 7) * 16;

  for (int k0 = 0; k0 < K; k0 += 32) {
    short8 a0 = *(const short8*)&A[(size_t)(row0 + ar) * K + k0 + ac];
    short8 a1 = *(const short8*)&A[(size_t)(row0 + 64 + ar) * K + k0 + ac];
    short8 b0 = *(const short8*)&B[(size_t)(k0 + bk) * N + col0 + bn0];
    short8 b1 = *(const short8*)&B[(size_t)(k0 + bk) * N + col0 + bn0 + 8];
    __syncthreads();   // previous iteration's fragment reads done
    *(short8*)&sA[ar * 40 + ac] = a0;
    *(short8*)&sA[(64 + ar) * 40 + ac] = a1;
#pragma unroll
    for (int e = 0; e < 8; e++) {
      sB[(bn0 + e) * 40 + bk] = (ushort)b0[e];
      sB[(bn0 + 8 + e) * 40 + bk] = (ushort)b1[e];
    }
    __syncthreads();
    short8 af[4], bfr[4];
#pragma unroll
    for (int i = 0; i < 4; i++)
      af[i] = *(const short8*)&sA[(wm + i * 16 + l16) * 40 + quad * 8];
#pragma unroll
    for (int j = 0; j < 4; j++)
      bfr[j] = *(const short8*)&sB[(wn + j * 16 + l16) * 40 + quad * 8];
#pragma unroll
    for (int i = 0; i < 4; i++)
#pragma unroll
      for (int j = 0; j < 4; j++)
        acc[i][j] = __builtin_amdgcn_mfma_f32_16x16x32_bf16(af[i], bfr[j], acc[i][j], 0, 0, 0);
  }

#pragma unroll
  for (int i = 0; i < 4; i++)
#pragma unroll
    for (int j = 0; j < 4; j++) {
      int r0 = row0 + wm + i * 16 + quad * 4;
      int c = col0 + wn + j * 16 + l16;
#pragma unroll
      for (int r = 0; r < 4; r++)
        stout(&C[(size_t)(r0 + r) * ldc + c], acc[i][j][r]);
    }
}

// ---------------- flash attention (causal), Q-tile 64, K/V-tile 64 ----------------
__global__ __launch_bounds__(256, 2) void flash_attn(
    const ushort* __restrict__ qkv, ushort* __restrict__ attn) {
  __shared__ ushort sK[64 * 136];    // [t][hd], stride 136
  __shared__ ushort sVt[128 * 72];   // [hd][t], stride 72
  __shared__ ushort sP[4 * 16 * 72]; // per-wave P, [q][t], stride 72

  const int tid = threadIdx.x;
  const int w = tid >> 6, l = tid & 63;
  const int quad = l >> 4, l16 = l & 15;
  const int qt = (int)gridDim.x - 1 - (int)blockIdx.x;  // big tiles first
  const int bh = blockIdx.y;
  const int b = bh >> 4, h = bh & 15;
  const int q0 = qt * 64;
  const size_t rowbase = (size_t)b * T_SEQ;

  const ushort* qptr = qkv + (rowbase + q0 + w * 16 + l16) * NQKV + h * HDIM + quad * 8;
  short8 qf[4];
#pragma unroll
  for (int s = 0; s < 4; s++) qf[s] = *(const short8*)(qptr + s * 32);

  floatx4 o[8];
  const floatx4 zero = {0.f, 0.f, 0.f, 0.f};
#pragma unroll
  for (int n = 0; n < 8; n++) o[n] = zero;
  float m_i[4] = {NEG_BIG, NEG_BIG, NEG_BIG, NEG_BIG};
  float l_i[4] = {0.f, 0.f, 0.f, 0.f};

  const int krow = tid >> 4;        // K staging: row c*16+krow, cols kcol..+7
  const int kcol = (tid & 15) * 8;
  const ushort* gK = qkv + rowbase * NQKV + 2048 + h * HDIM + kcol;
  const int v_hd0 = (tid & 15) * 8; // V staging: hd v_hd0..+7, t pair v_t0(+32c)
  const int v_t0 = 2 * (tid >> 4);
  const ushort* gV = qkv + rowbase * NQKV + 4096 + h * HDIM + v_hd0;

  const float scale = 0.08838834764831845f;  // 1/sqrt(128)
  const int nkt = qt + 1;
  for (int kt = 0; kt < nkt; kt++) {
    short8 kreg[4];
#pragma unroll
    for (int c = 0; c < 4; c++)
      kreg[c] = *(const short8*)(gK + (size_t)(kt * 64 + c * 16 + krow) * NQKV);
    short8 vr0[2], vr1[2];
#pragma unroll
    for (int c = 0; c < 2; c++) {
      const ushort* g = gV + (size_t)(kt * 64 + v_t0 + 32 * c) * NQKV;
      vr0[c] = *(const short8*)g;
      vr1[c] = *(const short8*)(g + NQKV);
    }
    __syncthreads();
#pragma unroll
    for (int c = 0; c < 4; c++)
      *(short8*)&sK[(c * 16 + krow) * 136 + kcol] = kreg[c];
#pragma unroll
    for (int c = 0; c < 2; c++) {
      int t0 = v_t0 + 32 * c;
#pragma unroll
      for (int j = 0; j < 8; j++) {
        unsigned pv = ((unsigned)(ushort)vr0[c][j]) | (((unsigned)(ushort)vr1[c][j]) << 16);
        *(unsigned*)&sVt[(v_hd0 + j) * 72 + t0] = pv;
      }
    }
    __syncthreads();

    // S = Q @ K^T
    floatx4 S[4];
#pragma unroll
    for (int j = 0; j < 4; j++) S[j] = zero;
#pragma unroll
    for (int s = 0; s < 4; s++)
#pragma unroll
      for (int j = 0; j < 4; j++) {
        short8 kf = *(const short8*)&sK[(j * 16 + l16) * 136 + s * 32 + quad * 8];
        S[j] = __builtin_amdgcn_mfma_f32_16x16x32_bf16(qf[s], kf, S[j], 0, 0, 0);
      }

    // scale + clamp + causal mask
    const bool diag = (kt == qt);
#pragma unroll
    for (int j = 0; j < 4; j++)
#pragma unroll
      for (int r = 0; r < 4; r++) {
        float v = S[j][r] * scale;
        v = fminf(fmaxf(v, -60.f), 60.f);
        if (diag && (j * 16 + l16 > w * 16 + quad * 4 + r)) v = NEG_BIG;
        S[j][r] = v;
      }

    // online softmax
    float alpha[4];
#pragma unroll
    for (int r = 0; r < 4; r++) {
      float v = fmaxf(fmaxf(S[0][r], S[1][r]), fmaxf(S[2][r], S[3][r]));
      v = fmaxf(v, __shfl_xor(v, 1, 16));
      v = fmaxf(v, __shfl_xor(v, 2, 16));
      v = fmaxf(v, __shfl_xor(v, 4, 16));
      v = fmaxf(v, __shfl_xor(v, 8, 16));
      float mn = fmaxf(m_i[r], v);
      alpha[r] = __expf(m_i[r] - mn);
      m_i[r] = mn;
    }
#pragma unroll
    for (int j = 0; j < 4; j++)
#pragma unroll
      for (int r = 0; r < 4; r++) S[j][r] = __expf(S[j][r] - m_i[r]);
#pragma unroll
    for (int r = 0; r < 4; r++)
      l_i[r] = l_i[r] * alpha[r] + S[0][r] + S[1][r] + S[2][r] + S[3][r];
#pragma unroll
    for (int n = 0; n < 8; n++)
#pragma unroll
      for (int r = 0; r < 4; r++) o[n][r] *= alpha[r];

    // P -> per-wave LDS (bf16), then PV
    ushort* myP = &sP[w * 16 * 72];
#pragma unroll
    for (int j = 0; j < 4; j++)
#pragma unroll
      for (int r = 0; r < 4; r++)
        myP[(quad * 4 + r) * 72 + j * 16 + l16] = f2bf(S[j][r]);
#pragma unroll
    for (int s = 0; s < 2; s++) {
      short8 pf = *(const short8*)&myP[l16 * 72 + s * 32 + quad * 8];
#pragma unroll
      for (int n = 0; n < 8; n++) {
        short8 vf = *(const short8*)&sVt[(n * 16 + l16) * 72 + s * 32 + quad * 8];
        o[n] = __builtin_amdgcn_mfma_f32_16x16x32_bf16(pf, vf, o[n], 0, 0, 0);
      }
    }
  }

  // epilogue: 1/l and store
#pragma unroll
  for (int r = 0; r < 4; r++) {
    float v = l_i[r];
    v += __shfl_xor(v, 1, 16);
    v += __shfl_xor(v, 2, 16);
    v += __shfl_xor(v, 4, 16);
    v += __shfl_xor(v, 8, 16);
    l_i[r] = 1.0f / v;
  }
#pragma unroll
  for (int n = 0; n < 8; n++) {
    int col = h * HDIM + n * 16 + l16;
#pragma unroll
    for (int r = 0; r < 4; r++) {
      int row = q0 + w * 16 + quad * 4 + r;
      attn[(rowbase + row) * DMODEL + col] = f2bf(o[n][r] * l_i[r]);
    }
  }
}

extern "C" void kernel_launch(void* const* d_in, const int* in_sizes, int n_in,
                              void* d_out, int out_size, void* d_ws, size_t ws_size,
                              hipStream_t stream) {
  const float* xf    = (const float*)d_in[0];   // [4096, 2048] fp32
  const float* Wqkvf = (const float*)d_in[1];   // [2048, 6144] fp32
  const float* Woutf = (const float*)d_in[2];   // [2048, 2048] fp32
  float* outf = (float*)d_out;                  // [4096, 2048] fp32

  // ws: qkv bf16 [4096,6144] at 0 (50.33MB peak). Final fp32 gemm output
  // overlays the then-dead qkv. d_out doubles as bf16 scratch:
  //   [0,16.8MB): x_bf16, later attn_bf16;  [16.8,25.2MB): W slice bf16.
  ushort* qkv   = (ushort*)d_ws;
  float*  of    = (float*)d_ws;                    // final gemm out (qkv dead)
  ushort* xb    = (ushort*)d_out;                  // x bf16 / attn bf16
  ushort* wb    = (ushort*)d_out + (size_t)4096 * 2048;  // W slice bf16
  ushort* attnb = xb;

  // x -> bf16 (8.4M elems)
  cvt2d<<<8192, 256, 0, stream>>>(xf, xb, 4096, 2048, 2048);

  // qkv = x @ Wqkv, one 2048-col slice at a time
  for (int s = 0; s < 3; s++) {
    cvt2d<<<4096, 256, 0, stream>>>(Wqkvf + s * 2048, wb, 2048, 2048, NQKV);
    gemm_bn<ushort><<<dim3(32, 16), 256, 0, stream>>>(
        xb, wb, qkv + s * 2048, 4096, 2048, 2048, NQKV);
  }

  // attention: qkv -> attn bf16 (overlays dead x_bf16 region of d_out)
  flash_attn<<<dim3(32, 32), 256, 0, stream>>>(qkv, attnb);

  // out = attn @ Wout, fp32 into dead qkv region, then copy to d_out
  cvt2d<<<4096, 256, 0, stream>>>(Woutf, wb, 2048, 2048, 2048);
  gemm_bn<float><<<dim3(32, 16), 256, 0, stream>>>(
      attnb, wb, of, 4096, 2048, 2048, DMODEL);
  hipMemcpyAsync(outf, of, (size_t)4096 * 2048 * 4, hipMemcpyDeviceToDevice, stream);
}

// Round 5
// 554.303 us; speedup vs baseline: 1.4155x; 1.4155x over previous
//
#include <hip/hip_runtime.h>

// Causal self-attention. fp32 in/out, bf16 MFMA compute inside.
// R5: gemms -> m97 global_load_lds structure (B^T via fused cvt-transpose);
// flash -> paired q-tiles (uniform work, shared K/V staging), register
// prefetch of next tile, XOR-swizzled V^T staging (kills 16-way write
// conflicts). MFMA 16x16x32 bf16 layouts (guide m89/m91):
//   A[m=lane&15][k=quad*8+j], B[k=quad*8+j][n=lane&15], C/D: row=quad*4+r, col=lane&15

typedef unsigned short ushort;
typedef __attribute__((ext_vector_type(8))) short short8;
typedef __attribute__((ext_vector_type(4))) float floatx4;

#define T_SEQ 2048
#define NQKV  6144
#define DMODEL 2048
#define HDIM  128
#define NEG_BIG (-3.0e38f)

__device__ __forceinline__ ushort f2bf(float f) {
  unsigned u = __float_as_uint(f);
  u += 0x7fffu + ((u >> 16) & 1u);   // RNE
  return (ushort)(u >> 16);
}
__device__ __forceinline__ void stout(ushort* p, float v) { *p = f2bf(v); }
__device__ __forceinline__ void stout(float* p, float v)  { *p = v; }

__device__ __forceinline__ void gload_lds16(const ushort* g, ushort* l) {
  __builtin_amdgcn_global_load_lds(
      (const __attribute__((address_space(1))) void*)g,
      (__attribute__((address_space(3))) void*)l,
      16, 0, 0);
}

// ---- fp32 [R x C] (row stride ld_in) -> dense bf16 [R x C] ----
__global__ void cvt2d(const float* __restrict__ in, ushort* __restrict__ out,
                      int R, int C, int ld_in) {
  int idx = blockIdx.x * blockDim.x + threadIdx.x;
  int c4 = C >> 2;
  if (idx >= R * c4) return;
  int r = idx / c4, c = (idx - r * c4) * 4;
  float4 v = *(const float4*)(in + (size_t)r * ld_in + c);
  ushort4 o;
  o.x = f2bf(v.x); o.y = f2bf(v.y); o.z = f2bf(v.z); o.w = f2bf(v.w);
  *(ushort4*)(out + (size_t)r * C + c) = o;
}

// ---- fp32 in[R][C] (row stride ld_in) -> bf16 out[C][R] dense ----
__global__ void cvt2dT(const float* __restrict__ in, ushort* __restrict__ out,
                       int R, int C, int ld_in) {
  __shared__ float tile[32][33];
  int c0 = blockIdx.x * 32, r0 = blockIdx.y * 32;
  int tx = threadIdx.x, ty = threadIdx.y;  // 32 x 8
#pragma unroll
  for (int q = 0; q < 4; q++)
    tile[ty + q * 8][tx] = in[(size_t)(r0 + ty + q * 8) * ld_in + c0 + tx];
  __syncthreads();
#pragma unroll
  for (int q = 0; q < 4; q++)
    out[(size_t)(c0 + ty + q * 8) * R + r0 + tx] = f2bf(tile[tx][ty + q * 8]);
}

// ---- C[M,N] = A[M,K] @ Bt[N,K]^T, bf16 in, OutT out (m97 structure) ----
template <typename OutT>
__global__ void gemm_bt(
    const ushort* __restrict__ A, const ushort* __restrict__ Bt,
    OutT* __restrict__ C, int M, int N, int K, int ldc) {
  __shared__ ushort sA[128 * 32];
  __shared__ ushort sB[128 * 32];
  const int tid = threadIdx.x;
  const int w = tid >> 6, l = tid & 63;
  const int quad = l >> 4, l16 = l & 15;
  const int row0 = blockIdx.x * 128, col0 = blockIdx.y * 128;
  const int wm = (w >> 1) * 64, wn = (w & 1) * 64;

  floatx4 acc[4][4];
  const floatx4 zero = {0.f, 0.f, 0.f, 0.f};
#pragma unroll
  for (int i = 0; i < 4; i++)
#pragma unroll
    for (int j = 0; j < 4; j++) acc[i][j] = zero;

  // staging: wave w covers rows w*16 + l/4 (+64), cols (l&3)*8 (DMA: base+lane*16B)
  const int srow = w * 16 + (l >> 2);
  const int scol = (l & 3) * 8;
  const ushort* gA = A + (size_t)(row0 + srow) * K + scol;
  const ushort* gB = Bt + (size_t)(col0 + srow) * K + scol;
  ushort* lA = &sA[(w * 16) * 32];
  ushort* lB = &sB[(w * 16) * 32];

  for (int k0 = 0; k0 < K; k0 += 32) {
    __syncthreads();
    gload_lds16(gA + k0, lA);
    gload_lds16(gA + k0 + (size_t)64 * K, lA + 64 * 32);
    gload_lds16(gB + k0, lB);
    gload_lds16(gB + k0 + (size_t)64 * K, lB + 64 * 32);
    __syncthreads();
    short8 af[4], bfr[4];
#pragma unroll
    for (int i = 0; i < 4; i++)
      af[i] = *(const short8*)&sA[(wm + i * 16 + l16) * 32 + quad * 8];
#pragma unroll
    for (int j = 0; j < 4; j++)
      bfr[j] = *(const short8*)&sB[(wn + j * 16 + l16) * 32 + quad * 8];
#pragma unroll
    for (int i = 0; i < 4; i++)
#pragma unroll
      for (int j = 0; j < 4; j++)
        acc[i][j] = __builtin_amdgcn_mfma_f32_16x16x32_bf16(af[i], bfr[j], acc[i][j], 0, 0, 0);
  }

#pragma unroll
  for (int i = 0; i < 4; i++)
#pragma unroll
    for (int j = 0; j < 4; j++) {
      int r0 = row0 + wm + i * 16 + quad * 4;
      int c = col0 + wn + j * 16 + l16;
#pragma unroll
      for (int r = 0; r < 4; r++)
        stout(&C[(size_t)(r0 + r) * ldc + c], acc[i][j][r]);
    }
}

// ---- flash attention (causal): block = q-tiles {x, 31-x}, shared K/V staging ----
// sVt swizzle: logical (hd, t) -> phys ushort
//   hd*72 + 2*(tw&3) + 8*((tw>>2) ^ ((hd>>3)&7)),  tw = t/2
// write banks 2-way (free), b128 reads stay 16B-aligned.
__global__ __launch_bounds__(256, 2) void flash_attn(
    const ushort* __restrict__ qkv, ushort* __restrict__ attn) {
  __shared__ ushort sK[64 * 136];    // [t][hd], stride 136
  __shared__ ushort sVt[128 * 72];   // swizzled [hd][t]
  __shared__ ushort sP[4 * 16 * 72]; // per-wave P, stride 72

  const int tid = threadIdx.x;
  const int w = tid >> 6, l = tid & 63;
  const int quad = l >> 4, l16 = l & 15;
  const int qtA = blockIdx.x;        // 0..15
  const int qtB = 31 - qtA;          // 16..31 (uniform 33 units/block)
  const int bh = blockIdx.y;
  const int b = bh >> 4, h = bh & 15;
  const size_t rowbase = (size_t)b * T_SEQ;

  short8 qfA[4], qfB[4];
  {
    const ushort* qpA = qkv + (rowbase + qtA * 64 + w * 16 + l16) * NQKV + h * HDIM + quad * 8;
    const ushort* qpB = qkv + (rowbase + qtB * 64 + w * 16 + l16) * NQKV + h * HDIM + quad * 8;
#pragma unroll
    for (int s = 0; s < 4; s++) { qfA[s] = *(const short8*)(qpA + s * 32); qfB[s] = *(const short8*)(qpB + s * 32); }
  }
  floatx4 oA[8], oB[8];
  const floatx4 zero = {0.f, 0.f, 0.f, 0.f};
#pragma unroll
  for (int n = 0; n < 8; n++) { oA[n] = zero; oB[n] = zero; }
  float mA[4], lA_[4], mB[4], lB_[4];
#pragma unroll
  for (int r = 0; r < 4; r++) { mA[r] = NEG_BIG; lA_[r] = 0.f; mB[r] = NEG_BIG; lB_[r] = 0.f; }

  const int krow = tid >> 4, kcol = (tid & 15) * 8;
  const ushort* gK = qkv + rowbase * NQKV + 2048 + h * HDIM + kcol;
  const int v_hd0 = (tid & 15) * 8;
  const int v_t0 = 2 * (tid >> 4);
  const ushort* gV = qkv + rowbase * NQKV + 4096 + h * HDIM + v_hd0;

  short8 kreg[4], vr0[2], vr1[2];
  auto loadKV = [&](int kt) {
#pragma unroll
    for (int c = 0; c < 4; c++)
      kreg[c] = *(const short8*)(gK + (size_t)(kt * 64 + c * 16 + krow) * NQKV);
#pragma unroll
    for (int c = 0; c < 2; c++) {
      const ushort* g = gV + (size_t)(kt * 64 + v_t0 + 32 * c) * NQKV;
      vr0[c] = *(const short8*)g;
      vr1[c] = *(const short8*)(g + NQKV);
    }
  };

  ushort* myP = &sP[w * 16 * 72];
  const float scale = 0.08838834764831845f;  // 1/sqrt(128)

  auto attn_step = [&](const short8* qf, floatx4* o, float* m_i, float* l_i, bool diag) {
    floatx4 S[4];
#pragma unroll
    for (int j = 0; j < 4; j++) S[j] = zero;
#pragma unroll
    for (int s = 0; s < 4; s++)
#pragma unroll
      for (int j = 0; j < 4; j++) {
        short8 kf = *(const short8*)&sK[(j * 16 + l16) * 136 + s * 32 + quad * 8];
        S[j] = __builtin_amdgcn_mfma_f32_16x16x32_bf16(qf[s], kf, S[j], 0, 0, 0);
      }
#pragma unroll
    for (int j = 0; j < 4; j++)
#pragma unroll
      for (int r = 0; r < 4; r++) {
        float v = S[j][r] * scale;
        if (diag && (j * 16 + l16 > w * 16 + quad * 4 + r)) v = NEG_BIG;
        S[j][r] = v;
      }
    float alpha[4];
#pragma unroll
    for (int r = 0; r < 4; r++) {
      float v = fmaxf(fmaxf(S[0][r], S[1][r]), fmaxf(S[2][r], S[3][r]));
      v = fmaxf(v, __shfl_xor(v, 1, 16));
      v = fmaxf(v, __shfl_xor(v, 2, 16));
      v = fmaxf(v, __shfl_xor(v, 4, 16));
      v = fmaxf(v, __shfl_xor(v, 8, 16));
      float mn = fmaxf(m_i[r], v);
      alpha[r] = __expf(m_i[r] - mn);
      m_i[r] = mn;
    }
#pragma unroll
    for (int j = 0; j < 4; j++)
#pragma unroll
      for (int r = 0; r < 4; r++) S[j][r] = __expf(S[j][r] - m_i[r]);
#pragma unroll
    for (int r = 0; r < 4; r++)
      l_i[r] = l_i[r] * alpha[r] + S[0][r] + S[1][r] + S[2][r] + S[3][r];
#pragma unroll
    for (int n = 0; n < 8; n++)
#pragma unroll
      for (int r = 0; r < 4; r++) o[n][r] *= alpha[r];
#pragma unroll
    for (int j = 0; j < 4; j++)
#pragma unroll
      for (int r = 0; r < 4; r++)
        myP[(quad * 4 + r) * 72 + j * 16 + l16] = f2bf(S[j][r]);
#pragma unroll
    for (int s = 0; s < 2; s++) {
      short8 pf = *(const short8*)&myP[l16 * 72 + s * 32 + quad * 8];
#pragma unroll
      for (int n = 0; n < 8; n++) {
        int hd = n * 16 + l16;
        short8 vf = *(const short8*)&sVt[hd * 72 + 8 * ((s * 4 + quad) ^ ((hd >> 3) & 7))];
        o[n] = __builtin_amdgcn_mfma_f32_16x16x32_bf16(pf, vf, o[n], 0, 0, 0);
      }
    }
  };

  loadKV(0);
  for (int kt = 0; kt <= qtB; kt++) {
    __syncthreads();   // prev iteration's LDS reads done
#pragma unroll
    for (int c = 0; c < 4; c++)
      *(short8*)&sK[(c * 16 + krow) * 136 + kcol] = kreg[c];
#pragma unroll
    for (int c = 0; c < 2; c++) {
      int tw = (v_t0 >> 1) + 16 * c;
#pragma unroll
      for (int j = 0; j < 8; j++) {
        int hd = v_hd0 + j;
        int phys = hd * 72 + 2 * (tw & 3) + 8 * ((tw >> 2) ^ ((hd >> 3) & 7));
        unsigned pv = ((unsigned)(ushort)vr0[c][j]) | (((unsigned)(ushort)vr1[c][j]) << 16);
        *(unsigned*)&sVt[phys] = pv;
      }
    }
    __syncthreads();
    if (kt < qtB) loadKV(kt + 1);  // prefetch across this tile's compute
    attn_step(qfB, oB, mB, lB_, kt == qtB);
    if (kt <= qtA) attn_step(qfA, oA, mA, lA_, kt == qtA);
  }

  auto epilogue = [&](floatx4* o, float* l_i, int qt) {
#pragma unroll
    for (int r = 0; r < 4; r++) {
      float v = l_i[r];
      v += __shfl_xor(v, 1, 16);
      v += __shfl_xor(v, 2, 16);
      v += __shfl_xor(v, 4, 16);
      v += __shfl_xor(v, 8, 16);
      l_i[r] = 1.0f / v;
    }
#pragma unroll
    for (int n = 0; n < 8; n++) {
      int col = h * HDIM + n * 16 + l16;
#pragma unroll
      for (int r = 0; r < 4; r++) {
        int row = qt * 64 + w * 16 + quad * 4 + r;
        attn[(rowbase + row) * DMODEL + col] = f2bf(o[n][r] * l_i[r]);
      }
    }
  };
  epilogue(oA, lA_, qtA);
  epilogue(oB, lB_, qtB);
}

extern "C" void kernel_launch(void* const* d_in, const int* in_sizes, int n_in,
                              void* d_out, int out_size, void* d_ws, size_t ws_size,
                              hipStream_t stream) {
  const float* xf    = (const float*)d_in[0];   // [4096, 2048] fp32
  const float* Wqkvf = (const float*)d_in[1];   // [2048, 6144] fp32
  const float* Woutf = (const float*)d_in[2];   // [2048, 2048] fp32
  float* outf = (float*)d_out;                  // [4096, 2048] fp32

  // ws: qkv bf16 [4096,6144] (50.33MB peak); final fp32 gemm overlays dead qkv.
  // d_out as scratch: [0,16.8M) x_bf16 (later attn_bf16); [16.8,25.2M) W^T bf16.
  ushort* qkv   = (ushort*)d_ws;
  float*  of    = (float*)d_ws;
  ushort* xb    = (ushort*)d_out;
  ushort* wbT   = (ushort*)d_out + (size_t)4096 * 2048;
  ushort* attnb = xb;

  cvt2d<<<8192, 256, 0, stream>>>(xf, xb, 4096, 2048, 2048);

  for (int s = 0; s < 3; s++) {
    cvt2dT<<<dim3(64, 64), dim3(32, 8), 0, stream>>>(Wqkvf + s * 2048, wbT, 2048, 2048, NQKV);
    gemm_bt<ushort><<<dim3(32, 16), 256, 0, stream>>>(
        xb, wbT, qkv + s * 2048, 4096, 2048, 2048, NQKV);
  }

  flash_attn<<<dim3(16, 32), 256, 0, stream>>>(qkv, attnb);

  cvt2dT<<<dim3(64, 64), dim3(32, 8), 0, stream>>>(Woutf, wbT, 2048, 2048, 2048);
  gemm_bt<float><<<dim3(32, 16), 256, 0, stream>>>(
      attnb, wbT, of, 4096, 2048, 2048, DMODEL);
  hipMemcpyAsync(outf, of, (size_t)4096 * 2048 * 4, hipMemcpyDeviceToDevice, stream);
}

// Round 6
// 498.144 us; speedup vs baseline: 1.5751x; 1.1127x over previous
//
#include <hip/hip_runtime.h>

// Causal self-attention. fp32 in/out, bf16 MFMA compute inside.
// R6: flash de-spilled (K via double-buffered global_load_lds DMA issued
// inside the compute phase; only V prefetched in regs), bh-major grid for
// XCD-local K/V sharing; GEMM un-sliced + direct d_out write when ws allows.
// MFMA 16x16x32 bf16 layouts (guide m89/m91):
//   A[m=lane&15][k=quad*8+j], B[k=quad*8+j][n=lane&15], C/D: row=quad*4+r, col=lane&15

typedef unsigned short ushort;
typedef __attribute__((ext_vector_type(8))) short short8;
typedef __attribute__((ext_vector_type(4))) float floatx4;

#define T_SEQ 2048
#define NQKV  6144
#define DMODEL 2048
#define HDIM  128
#define NEG_BIG (-3.0e38f)

__device__ __forceinline__ ushort f2bf(float f) {
  unsigned u = __float_as_uint(f);
  u += 0x7fffu + ((u >> 16) & 1u);   // RNE
  return (ushort)(u >> 16);
}
__device__ __forceinline__ void stout(ushort* p, float v) { *p = f2bf(v); }
__device__ __forceinline__ void stout(float* p, float v)  { *p = v; }

__device__ __forceinline__ void gload_lds16(const ushort* g, ushort* l) {
  __builtin_amdgcn_global_load_lds(
      (const __attribute__((address_space(1))) void*)g,
      (__attribute__((address_space(3))) void*)l,
      16, 0, 0);
}

// ---- fp32 [R x C] (row stride ld_in) -> dense bf16 [R x C] ----
__global__ void cvt2d(const float* __restrict__ in, ushort* __restrict__ out,
                      int R, int C, int ld_in) {
  int idx = blockIdx.x * blockDim.x + threadIdx.x;
  int c4 = C >> 2;
  if (idx >= R * c4) return;
  int r = idx / c4, c = (idx - r * c4) * 4;
  float4 v = *(const float4*)(in + (size_t)r * ld_in + c);
  ushort4 o;
  o.x = f2bf(v.x); o.y = f2bf(v.y); o.z = f2bf(v.z); o.w = f2bf(v.w);
  *(ushort4*)(out + (size_t)r * C + c) = o;
}

// ---- fp32 in[R][C] (row stride ld_in) -> bf16 out[C][R] dense ----
__global__ void cvt2dT(const float* __restrict__ in, ushort* __restrict__ out,
                       int R, int C, int ld_in) {
  __shared__ float tile[32][33];
  int c0 = blockIdx.x * 32, r0 = blockIdx.y * 32;
  int tx = threadIdx.x, ty = threadIdx.y;  // 32 x 8
#pragma unroll
  for (int q = 0; q < 4; q++)
    tile[ty + q * 8][tx] = in[(size_t)(r0 + ty + q * 8) * ld_in + c0 + tx];
  __syncthreads();
#pragma unroll
  for (int q = 0; q < 4; q++)
    out[(size_t)(c0 + ty + q * 8) * R + r0 + tx] = f2bf(tile[tx][ty + q * 8]);
}

// ---- C[M,N] = A[M,K] @ Bt[N,K]^T, bf16 in, OutT out (m97 structure) ----
template <typename OutT>
__global__ void gemm_bt(
    const ushort* __restrict__ A, const ushort* __restrict__ Bt,
    OutT* __restrict__ C, int M, int N, int K, int ldc) {
  __shared__ ushort sA[128 * 32];
  __shared__ ushort sB[128 * 32];
  const int tid = threadIdx.x;
  const int w = tid >> 6, l = tid & 63;
  const int quad = l >> 4, l16 = l & 15;
  const int row0 = blockIdx.x * 128, col0 = blockIdx.y * 128;
  const int wm = (w >> 1) * 64, wn = (w & 1) * 64;

  floatx4 acc[4][4];
  const floatx4 zero = {0.f, 0.f, 0.f, 0.f};
#pragma unroll
  for (int i = 0; i < 4; i++)
#pragma unroll
    for (int j = 0; j < 4; j++) acc[i][j] = zero;

  const int srow = w * 16 + (l >> 2);
  const int scol = (l & 3) * 8;
  const ushort* gA = A + (size_t)(row0 + srow) * K + scol;
  const ushort* gB = Bt + (size_t)(col0 + srow) * K + scol;
  ushort* lA = &sA[(w * 16) * 32];
  ushort* lB = &sB[(w * 16) * 32];

  for (int k0 = 0; k0 < K; k0 += 32) {
    __syncthreads();
    gload_lds16(gA + k0, lA);
    gload_lds16(gA + k0 + (size_t)64 * K, lA + 64 * 32);
    gload_lds16(gB + k0, lB);
    gload_lds16(gB + k0 + (size_t)64 * K, lB + 64 * 32);
    __syncthreads();
    short8 af[4], bfr[4];
#pragma unroll
    for (int i = 0; i < 4; i++)
      af[i] = *(const short8*)&sA[(wm + i * 16 + l16) * 32 + quad * 8];
#pragma unroll
    for (int j = 0; j < 4; j++)
      bfr[j] = *(const short8*)&sB[(wn + j * 16 + l16) * 32 + quad * 8];
#pragma unroll
    for (int i = 0; i < 4; i++)
#pragma unroll
      for (int j = 0; j < 4; j++)
        acc[i][j] = __builtin_amdgcn_mfma_f32_16x16x32_bf16(af[i], bfr[j], acc[i][j], 0, 0, 0);
  }

#pragma unroll
  for (int i = 0; i < 4; i++)
#pragma unroll
    for (int j = 0; j < 4; j++) {
      int r0 = row0 + wm + i * 16 + quad * 4;
      int c = col0 + wn + j * 16 + l16;
#pragma unroll
      for (int r = 0; r < 4; r++)
        stout(&C[(size_t)(r0 + r) * ldc + c], acc[i][j][r]);
    }
}

// ---- flash attention (causal): block = q-tiles {y, 31-y}; grid (bh, qtA) ----
// K: double-buffered DMA (global_load_lds, unpadded [64][128]); V: 16-VGPR
// register prefetch + swizzled LDS transpose. DMA for tile kt+1 is issued
// after the staging barrier of tile kt, so its latency hides under compute.
__global__ __launch_bounds__(256, 2) void flash_attn(
    const ushort* __restrict__ qkv, ushort* __restrict__ attn) {
  __shared__ ushort sK[2][64 * 128]; // DMA target: unpadded
  __shared__ ushort sVt[128 * 72];   // swizzled [hd][t]
  __shared__ ushort sP[4 * 16 * 72]; // per-wave P, stride 72

  const int tid = threadIdx.x;
  const int w = tid >> 6, l = tid & 63;
  const int quad = l >> 4, l16 = l & 15;
  const int bh = blockIdx.x;         // bh-major => same-bh blocks on one XCD
  const int qtA = blockIdx.y;        // 0..15
  const int qtB = 31 - qtA;          // uniform 33 units/block
  const int b = bh >> 4, h = bh & 15;
  const size_t rowbase = (size_t)b * T_SEQ;

  short8 qfA[4], qfB[4];
  {
    const ushort* qpA = qkv + (rowbase + qtA * 64 + w * 16 + l16) * NQKV + h * HDIM + quad * 8;
    const ushort* qpB = qkv + (rowbase + qtB * 64 + w * 16 + l16) * NQKV + h * HDIM + quad * 8;
#pragma unroll
    for (int s = 0; s < 4; s++) { qfA[s] = *(const short8*)(qpA + s * 32); qfB[s] = *(const short8*)(qpB + s * 32); }
  }
  floatx4 oA[8], oB[8];
  const floatx4 zero = {0.f, 0.f, 0.f, 0.f};
#pragma unroll
  for (int n = 0; n < 8; n++) { oA[n] = zero; oB[n] = zero; }
  float mA[4], lAi[4], mB[4], lBi[4];
#pragma unroll
  for (int r = 0; r < 4; r++) { mA[r] = NEG_BIG; lAi[r] = 0.f; mB[r] = NEG_BIG; lBi[r] = 0.f; }

  // K DMA: instr c stages rows w*16+c*4 .. +3; lane l -> row +(l>>4), col (l&15)*8
  const ushort* gK = qkv + (rowbase + w * 16 + (l >> 4)) * NQKV + 2048 + h * HDIM + (l & 15) * 8;
  // V: thread covers hd v_hd0..+7, t pair v_t0 (+32c)
  const int v_hd0 = (tid & 15) * 8;
  const int v_t0 = 2 * (tid >> 4);
  const ushort* gV = qkv + rowbase * NQKV + 4096 + h * HDIM + v_hd0;

  auto issueK = [&](int kt, int buf) {
#pragma unroll
    for (int c = 0; c < 4; c++)
      gload_lds16(gK + (size_t)(kt * 64 + c * 4) * NQKV, &sK[buf][(w * 16 + c * 4) * 128]);
  };
  short8 vcur[4], vnxt[4];  // [0..1]=row t0, [2..3]=row t0+1 (c pairs)
  auto loadV = [&](int kt, short8* dst) {
#pragma unroll
    for (int c = 0; c < 2; c++) {
      const ushort* g = gV + (size_t)(kt * 64 + v_t0 + 32 * c) * NQKV;
      dst[c] = *(const short8*)g;
      dst[2 + c] = *(const short8*)(g + NQKV);
    }
  };

  ushort* myP = &sP[w * 16 * 72];
  const float scale = 0.08838834764831845f;  // 1/sqrt(128)

  auto attn_step = [&](const short8* qf, floatx4* o, float* m_i, float* l_i,
                       bool diag, int buf) {
    floatx4 S[4];
#pragma unroll
    for (int j = 0; j < 4; j++) S[j] = zero;
#pragma unroll
    for (int s = 0; s < 4; s++)
#pragma unroll
      for (int j = 0; j < 4; j++) {
        short8 kf = *(const short8*)&sK[buf][(j * 16 + l16) * 128 + s * 32 + quad * 8];
        S[j] = __builtin_amdgcn_mfma_f32_16x16x32_bf16(qf[s], kf, S[j], 0, 0, 0);
      }
#pragma unroll
    for (int j = 0; j < 4; j++)
#pragma unroll
      for (int r = 0; r < 4; r++) {
        float v = S[j][r] * scale;
        if (diag && (j * 16 + l16 > w * 16 + quad * 4 + r)) v = NEG_BIG;
        S[j][r] = v;
      }
    float alpha[4];
#pragma unroll
    for (int r = 0; r < 4; r++) {
      float v = fmaxf(fmaxf(S[0][r], S[1][r]), fmaxf(S[2][r], S[3][r]));
      v = fmaxf(v, __shfl_xor(v, 1, 16));
      v = fmaxf(v, __shfl_xor(v, 2, 16));
      v = fmaxf(v, __shfl_xor(v, 4, 16));
      v = fmaxf(v, __shfl_xor(v, 8, 16));
      float mn = fmaxf(m_i[r], v);
      alpha[r] = __expf(m_i[r] - mn);
      m_i[r] = mn;
    }
#pragma unroll
    for (int j = 0; j < 4; j++)
#pragma unroll
      for (int r = 0; r < 4; r++) S[j][r] = __expf(S[j][r] - m_i[r]);
#pragma unroll
    for (int r = 0; r < 4; r++)
      l_i[r] = l_i[r] * alpha[r] + S[0][r] + S[1][r] + S[2][r] + S[3][r];
#pragma unroll
    for (int n = 0; n < 8; n++)
#pragma unroll
      for (int r = 0; r < 4; r++) o[n][r] *= alpha[r];
#pragma unroll
    for (int j = 0; j < 4; j++)
#pragma unroll
      for (int r = 0; r < 4; r++)
        myP[(quad * 4 + r) * 72 + j * 16 + l16] = f2bf(S[j][r]);
#pragma unroll
    for (int s = 0; s < 2; s++) {
      short8 pf = *(const short8*)&myP[l16 * 72 + s * 32 + quad * 8];
#pragma unroll
      for (int n = 0; n < 8; n++) {
        int hd = n * 16 + l16;
        short8 vf = *(const short8*)&sVt[hd * 72 + 8 * ((s * 4 + quad) ^ ((hd >> 3) & 7))];
        o[n] = __builtin_amdgcn_mfma_f32_16x16x32_bf16(pf, vf, o[n], 0, 0, 0);
      }
    }
  };

  issueK(0, 0);
  loadV(0, vcur);
  for (int kt = 0; kt <= qtB; kt++) {
    const int buf = kt & 1;
    __syncthreads();   // drains K DMA for buf (vmcnt) + prev iter's LDS reads
    // V^T staging (swizzled: write banks 2-way, reads b128 16B-aligned)
#pragma unroll
    for (int c = 0; c < 2; c++) {
      int tw = (v_t0 >> 1) + 16 * c;
#pragma unroll
      for (int j = 0; j < 8; j++) {
        int hd = v_hd0 + j;
        int phys = hd * 72 + 2 * (tw & 3) + 8 * ((tw >> 2) ^ ((hd >> 3) & 7));
        unsigned pv = ((unsigned)(ushort)vcur[c][j]) | (((unsigned)(ushort)vcur[2 + c][j]) << 16);
        *(unsigned*)&sVt[phys] = pv;
      }
    }
    __syncthreads();   // Vt visible (lgkm only; next DMA not yet issued)
    if (kt < qtB) {    // prefetch next tile during compute
      issueK(kt + 1, buf ^ 1);
      loadV(kt + 1, vnxt);
    }
    attn_step(qfB, oB, mB, lBi, kt == qtB, buf);
    if (kt <= qtA) attn_step(qfA, oA, mA, lAi, kt == qtA, buf);
    if (kt < qtB) {
#pragma unroll
      for (int c = 0; c < 4; c++) vcur[c] = vnxt[c];
    }
  }

  auto epilogue = [&](floatx4* o, float* l_i, int qt) {
#pragma unroll
    for (int r = 0; r < 4; r++) {
      float v = l_i[r];
      v += __shfl_xor(v, 1, 16);
      v += __shfl_xor(v, 2, 16);
      v += __shfl_xor(v, 4, 16);
      v += __shfl_xor(v, 8, 16);
      l_i[r] = 1.0f / v;
    }
#pragma unroll
    for (int n = 0; n < 8; n++) {
      int col = h * HDIM + n * 16 + l16;
#pragma unroll
      for (int r = 0; r < 4; r++) {
        int row = qt * 64 + w * 16 + quad * 4 + r;
        attn[(rowbase + row) * DMODEL + col] = f2bf(o[n][r] * l_i[r]);
      }
    }
  };
  epilogue(oA, lAi, qtA);
  epilogue(oB, lBi, qtB);
}

extern "C" void kernel_launch(void* const* d_in, const int* in_sizes, int n_in,
                              void* d_out, int out_size, void* d_ws, size_t ws_size,
                              hipStream_t stream) {
  const float* xf    = (const float*)d_in[0];   // [4096, 2048] fp32
  const float* Wqkvf = (const float*)d_in[1];   // [2048, 6144] fp32
  const float* Woutf = (const float*)d_in[2];   // [2048, 2048] fp32
  float* outf = (float*)d_out;                  // [4096, 2048] fp32
  char* ws = (char*)d_ws;

  const size_t SZ_QKV  = (size_t)4096 * 6144 * 2;  // 50.33 MB
  const size_t SZ_ATTN = (size_t)4096 * 2048 * 2;  // 16.78 MB
  const size_t SZ_WQT  = (size_t)6144 * 2048 * 2;  // 25.17 MB

  ushort* xb = (ushort*)d_out;  // bf16 x in d_out scratch (dead before final write)
  cvt2d<<<8192, 256, 0, stream>>>(xf, xb, 4096, 2048, 2048);

  if (ws_size >= SZ_QKV + SZ_ATTN + SZ_WQT) {
    // Tier A: un-sliced QKV gemm, attn in ws, final gemm direct to d_out.
    ushort* qkv   = (ushort*)ws;
    ushort* attnb = (ushort*)(ws + SZ_QKV);
    ushort* WT    = (ushort*)(ws + SZ_QKV + SZ_ATTN);
    cvt2dT<<<dim3(192, 64), dim3(32, 8), 0, stream>>>(Wqkvf, WT, 2048, 6144, NQKV);
    gemm_bt<ushort><<<dim3(32, 48), 256, 0, stream>>>(xb, WT, qkv, 4096, 6144, 2048, NQKV);
    flash_attn<<<dim3(32, 16), 256, 0, stream>>>(qkv, attnb);
    cvt2dT<<<dim3(64, 64), dim3(32, 8), 0, stream>>>(Woutf, WT, 2048, 2048, 2048);
    gemm_bt<float><<<dim3(32, 16), 256, 0, stream>>>(attnb, WT, outf, 4096, 2048, 2048, DMODEL);
  } else {
    // Tier B (ws >= 50.33 MB): R5 flow — sliced QKV, attn in d_out, memcpy back.
    ushort* qkv   = (ushort*)ws;
    float*  of    = (float*)ws;
    ushort* wbT   = (ushort*)d_out + (size_t)4096 * 2048;
    ushort* attnb = xb;
    for (int s = 0; s < 3; s++) {
      cvt2dT<<<dim3(64, 64), dim3(32, 8), 0, stream>>>(Wqkvf + s * 2048, wbT, 2048, 2048, NQKV);
      gemm_bt<ushort><<<dim3(32, 16), 256, 0, stream>>>(xb, wbT, qkv + s * 2048, 4096, 2048, 2048, NQKV);
    }
    flash_attn<<<dim3(32, 16), 256, 0, stream>>>(qkv, attnb);
    cvt2dT<<<dim3(64, 64), dim3(32, 8), 0, stream>>>(Woutf, wbT, 2048, 2048, 2048);
    gemm_bt<float><<<dim3(32, 16), 256, 0, stream>>>(attnb, wbT, of, 4096, 2048, 2048, DMODEL);
    hipMemcpyAsync(outf, of, (size_t)4096 * 2048 * 4, hipMemcpyDeviceToDevice, stream);
  }
}

// Round 7
// 396.263 us; speedup vs baseline: 1.9801x; 1.2571x over previous
//
#include <hip/hip_runtime.h>

// Causal self-attention. fp32 in/out, bf16 MFMA compute inside.
// R7: flash un-paired (kills the ~350MB/dispatch spill traffic of R5/R6's
// paired design); load balance via big-blocks-first dispatch instead. K DMA
// kept, now group-padded (32B pad per 4-row group -> 4-way instead of 16-way
// read conflicts). V register-prefetch + swizzled LDS transpose unchanged.
// MFMA 16x16x32 bf16 layouts (guide m89/m91):
//   A[m=lane&15][k=quad*8+j], B[k=quad*8+j][n=lane&15], C/D: row=quad*4+r, col=lane&15

typedef unsigned short ushort;
typedef __attribute__((ext_vector_type(8))) short short8;
typedef __attribute__((ext_vector_type(4))) float floatx4;

#define T_SEQ 2048
#define NQKV  6144
#define DMODEL 2048
#define HDIM  128
#define NEG_BIG (-3.0e38f)

__device__ __forceinline__ ushort f2bf(float f) {
  unsigned u = __float_as_uint(f);
  u += 0x7fffu + ((u >> 16) & 1u);   // RNE
  return (ushort)(u >> 16);
}
__device__ __forceinline__ void stout(ushort* p, float v) { *p = f2bf(v); }
__device__ __forceinline__ void stout(float* p, float v)  { *p = v; }

__device__ __forceinline__ void gload_lds16(const ushort* g, ushort* l) {
  __builtin_amdgcn_global_load_lds(
      (const __attribute__((address_space(1))) void*)g,
      (__attribute__((address_space(3))) void*)l,
      16, 0, 0);
}

// ---- fp32 [R x C] (row stride ld_in) -> dense bf16 [R x C] ----
__global__ void cvt2d(const float* __restrict__ in, ushort* __restrict__ out,
                      int R, int C, int ld_in) {
  int idx = blockIdx.x * blockDim.x + threadIdx.x;
  int c4 = C >> 2;
  if (idx >= R * c4) return;
  int r = idx / c4, c = (idx - r * c4) * 4;
  float4 v = *(const float4*)(in + (size_t)r * ld_in + c);
  ushort4 o;
  o.x = f2bf(v.x); o.y = f2bf(v.y); o.z = f2bf(v.z); o.w = f2bf(v.w);
  *(ushort4*)(out + (size_t)r * C + c) = o;
}

// ---- fp32 in[R][C] (row stride ld_in) -> bf16 out[C][R] dense ----
__global__ void cvt2dT(const float* __restrict__ in, ushort* __restrict__ out,
                       int R, int C, int ld_in) {
  __shared__ float tile[32][33];
  int c0 = blockIdx.x * 32, r0 = blockIdx.y * 32;
  int tx = threadIdx.x, ty = threadIdx.y;  // 32 x 8
#pragma unroll
  for (int q = 0; q < 4; q++)
    tile[ty + q * 8][tx] = in[(size_t)(r0 + ty + q * 8) * ld_in + c0 + tx];
  __syncthreads();
#pragma unroll
  for (int q = 0; q < 4; q++)
    out[(size_t)(c0 + ty + q * 8) * R + r0 + tx] = f2bf(tile[tx][ty + q * 8]);
}

// ---- C[M,N] = A[M,K] @ Bt[N,K]^T, bf16 in, OutT out (m97 structure) ----
template <typename OutT>
__global__ void gemm_bt(
    const ushort* __restrict__ A, const ushort* __restrict__ Bt,
    OutT* __restrict__ C, int M, int N, int K, int ldc) {
  __shared__ ushort sA[128 * 32];
  __shared__ ushort sB[128 * 32];
  const int tid = threadIdx.x;
  const int w = tid >> 6, l = tid & 63;
  const int quad = l >> 4, l16 = l & 15;
  const int row0 = blockIdx.x * 128, col0 = blockIdx.y * 128;
  const int wm = (w >> 1) * 64, wn = (w & 1) * 64;

  floatx4 acc[4][4];
  const floatx4 zero = {0.f, 0.f, 0.f, 0.f};
#pragma unroll
  for (int i = 0; i < 4; i++)
#pragma unroll
    for (int j = 0; j < 4; j++) acc[i][j] = zero;

  const int srow = w * 16 + (l >> 2);
  const int scol = (l & 3) * 8;
  const ushort* gA = A + (size_t)(row0 + srow) * K + scol;
  const ushort* gB = Bt + (size_t)(col0 + srow) * K + scol;
  ushort* lA = &sA[(w * 16) * 32];
  ushort* lB = &sB[(w * 16) * 32];

  for (int k0 = 0; k0 < K; k0 += 32) {
    __syncthreads();
    gload_lds16(gA + k0, lA);
    gload_lds16(gA + k0 + (size_t)64 * K, lA + 64 * 32);
    gload_lds16(gB + k0, lB);
    gload_lds16(gB + k0 + (size_t)64 * K, lB + 64 * 32);
    __syncthreads();
    short8 af[4], bfr[4];
#pragma unroll
    for (int i = 0; i < 4; i++)
      af[i] = *(const short8*)&sA[(wm + i * 16 + l16) * 32 + quad * 8];
#pragma unroll
    for (int j = 0; j < 4; j++)
      bfr[j] = *(const short8*)&sB[(wn + j * 16 + l16) * 32 + quad * 8];
#pragma unroll
    for (int i = 0; i < 4; i++)
#pragma unroll
      for (int j = 0; j < 4; j++)
        acc[i][j] = __builtin_amdgcn_mfma_f32_16x16x32_bf16(af[i], bfr[j], acc[i][j], 0, 0, 0);
  }

#pragma unroll
  for (int i = 0; i < 4; i++)
#pragma unroll
    for (int j = 0; j < 4; j++) {
      int r0 = row0 + wm + i * 16 + quad * 4;
      int c = col0 + wn + j * 16 + l16;
#pragma unroll
      for (int r = 0; r < 4; r++)
        stout(&C[(size_t)(r0 + r) * ldc + c], acc[i][j][r]);
    }
}

// ---- flash attention (causal): one 64-row q-tile per block; grid (bh, qtOrd) ----
// sK: 2 buffers, 16 groups each; group = 4 rows x 128 ushort + 16-ushort pad
// (528 ushort stride). DMA writes one group per instruction (1024B contig);
// the pad staggers groups by 8 banks -> K-fragment b128 reads are 4-way.
__global__ __launch_bounds__(256, 2) void flash_attn(
    const ushort* __restrict__ qkv, ushort* __restrict__ attn) {
  __shared__ ushort sK[2][16 * 528];
  __shared__ ushort sVt[128 * 72];   // swizzled [hd][t]
  __shared__ ushort sP[4 * 16 * 72]; // per-wave P, stride 72

  const int tid = threadIdx.x;
  const int w = tid >> 6, l = tid & 63;
  const int quad = l >> 4, l16 = l & 15;
  const int bh = blockIdx.x;            // bh-major: same-bh blocks share an XCD
  const int qt = 31 - (int)blockIdx.y;  // biggest blocks dispatch first
  const int b = bh >> 4, h = bh & 15;
  const size_t rowbase = (size_t)b * T_SEQ;

  short8 qf[4];
  {
    const ushort* qp = qkv + (rowbase + qt * 64 + w * 16 + l16) * NQKV + h * HDIM + quad * 8;
#pragma unroll
    for (int s = 0; s < 4; s++) qf[s] = *(const short8*)(qp + s * 32);
  }
  floatx4 o[8];
  const floatx4 zero = {0.f, 0.f, 0.f, 0.f};
#pragma unroll
  for (int n = 0; n < 8; n++) o[n] = zero;
  float m_i[4], l_i[4];
#pragma unroll
  for (int r = 0; r < 4; r++) { m_i[r] = NEG_BIG; l_i[r] = 0.f; }

  // K DMA: instr c stages group w*4+c (rows w*16+c*4..+3);
  // lane l -> row +(l>>4), cols (l&15)*8..+7.
  const ushort* gK = qkv + (rowbase + w * 16 + (l >> 4)) * NQKV + 2048 + h * HDIM + (l & 15) * 8;
  auto issueK = [&](int kt, int buf) {
#pragma unroll
    for (int c = 0; c < 4; c++)
      gload_lds16(gK + (size_t)(kt * 64 + c * 4) * NQKV, &sK[buf][(w * 4 + c) * 528]);
  };
  // V: thread covers hd v_hd0..+7, t pair v_t0 (+32c)
  const int v_hd0 = (tid & 15) * 8;
  const int v_t0 = 2 * (tid >> 4);
  const ushort* gV = qkv + rowbase * NQKV + 4096 + h * HDIM + v_hd0;
  short8 vcur[4], vnxt[4];  // [0..1]=row t0 (c=0,1), [2..3]=row t0+1
  auto loadV = [&](int kt, short8* dst) {
#pragma unroll
    for (int c = 0; c < 2; c++) {
      const ushort* g = gV + (size_t)(kt * 64 + v_t0 + 32 * c) * NQKV;
      dst[c] = *(const short8*)g;
      dst[2 + c] = *(const short8*)(g + NQKV);
    }
  };

  ushort* myP = &sP[w * 16 * 72];
  const float scale = 0.08838834764831845f;  // 1/sqrt(128)

  auto attn_step = [&](bool diag, int buf) {
    floatx4 S[4];
#pragma unroll
    for (int j = 0; j < 4; j++) S[j] = zero;
#pragma unroll
    for (int s = 0; s < 4; s++)
#pragma unroll
      for (int j = 0; j < 4; j++) {
        int row = j * 16 + l16;
        short8 kf = *(const short8*)&sK[buf][(row >> 2) * 528 + (row & 3) * 128 + s * 32 + quad * 8];
        S[j] = __builtin_amdgcn_mfma_f32_16x16x32_bf16(qf[s], kf, S[j], 0, 0, 0);
      }
#pragma unroll
    for (int j = 0; j < 4; j++)
#pragma unroll
      for (int r = 0; r < 4; r++) {
        float v = S[j][r] * scale;
        if (diag && (j * 16 + l16 > w * 16 + quad * 4 + r)) v = NEG_BIG;
        S[j][r] = v;
      }
    float alpha[4];
#pragma unroll
    for (int r = 0; r < 4; r++) {
      float v = fmaxf(fmaxf(S[0][r], S[1][r]), fmaxf(S[2][r], S[3][r]));
      v = fmaxf(v, __shfl_xor(v, 1, 16));
      v = fmaxf(v, __shfl_xor(v, 2, 16));
      v = fmaxf(v, __shfl_xor(v, 4, 16));
      v = fmaxf(v, __shfl_xor(v, 8, 16));
      float mn = fmaxf(m_i[r], v);
      alpha[r] = __expf(m_i[r] - mn);
      m_i[r] = mn;
    }
#pragma unroll
    for (int j = 0; j < 4; j++)
#pragma unroll
      for (int r = 0; r < 4; r++) S[j][r] = __expf(S[j][r] - m_i[r]);
#pragma unroll
    for (int r = 0; r < 4; r++)
      l_i[r] = l_i[r] * alpha[r] + S[0][r] + S[1][r] + S[2][r] + S[3][r];
#pragma unroll
    for (int n = 0; n < 8; n++)
#pragma unroll
      for (int r = 0; r < 4; r++) o[n][r] *= alpha[r];
#pragma unroll
    for (int j = 0; j < 4; j++)
#pragma unroll
      for (int r = 0; r < 4; r++)
        myP[(quad * 4 + r) * 72 + j * 16 + l16] = f2bf(S[j][r]);
#pragma unroll
    for (int s = 0; s < 2; s++) {
      short8 pf = *(const short8*)&myP[l16 * 72 + s * 32 + quad * 8];
#pragma unroll
      for (int n = 0; n < 8; n++) {
        int hd = n * 16 + l16;
        short8 vf = *(const short8*)&sVt[hd * 72 + 8 * ((s * 4 + quad) ^ ((hd >> 3) & 7))];
        o[n] = __builtin_amdgcn_mfma_f32_16x16x32_bf16(pf, vf, o[n], 0, 0, 0);
      }
    }
  };

  issueK(0, 0);
  loadV(0, vcur);
  for (int kt = 0; kt <= qt; kt++) {
    const int buf = kt & 1;
    __syncthreads();   // drains this buf's K DMA (vmcnt0) + prev iter LDS reads
    // V^T staging (swizzled: write banks 2-way, reads b128 16B-aligned)
#pragma unroll
    for (int c = 0; c < 2; c++) {
      int tw = (v_t0 >> 1) + 16 * c;
#pragma unroll
      for (int j = 0; j < 8; j++) {
        int hd = v_hd0 + j;
        int phys = hd * 72 + 2 * (tw & 3) + 8 * ((tw >> 2) ^ ((hd >> 3) & 7));
        unsigned pv = ((unsigned)(ushort)vcur[c][j]) | (((unsigned)(ushort)vcur[2 + c][j]) << 16);
        *(unsigned*)&sVt[phys] = pv;
      }
    }
    __syncthreads();
    if (kt < qt) {     // prefetch next tile during this tile's compute
      issueK(kt + 1, buf ^ 1);
      loadV(kt + 1, vnxt);
    }
    attn_step(kt == qt, buf);
    if (kt < qt) {
#pragma unroll
      for (int c = 0; c < 4; c++) vcur[c] = vnxt[c];
    }
  }

  // epilogue: 1/l and store
#pragma unroll
  for (int r = 0; r < 4; r++) {
    float v = l_i[r];
    v += __shfl_xor(v, 1, 16);
    v += __shfl_xor(v, 2, 16);
    v += __shfl_xor(v, 4, 16);
    v += __shfl_xor(v, 8, 16);
    l_i[r] = 1.0f / v;
  }
#pragma unroll
  for (int n = 0; n < 8; n++) {
    int col = h * HDIM + n * 16 + l16;
#pragma unroll
    for (int r = 0; r < 4; r++) {
      int row = qt * 64 + w * 16 + quad * 4 + r;
      attn[(rowbase + row) * DMODEL + col] = f2bf(o[n][r] * l_i[r]);
    }
  }
}

extern "C" void kernel_launch(void* const* d_in, const int* in_sizes, int n_in,
                              void* d_out, int out_size, void* d_ws, size_t ws_size,
                              hipStream_t stream) {
  const float* xf    = (const float*)d_in[0];   // [4096, 2048] fp32
  const float* Wqkvf = (const float*)d_in[1];   // [2048, 6144] fp32
  const float* Woutf = (const float*)d_in[2];   // [2048, 2048] fp32
  float* outf = (float*)d_out;                  // [4096, 2048] fp32
  char* ws = (char*)d_ws;

  const size_t SZ_QKV  = (size_t)4096 * 6144 * 2;  // 50.33 MB
  const size_t SZ_ATTN = (size_t)4096 * 2048 * 2;  // 16.78 MB
  const size_t SZ_WQT  = (size_t)6144 * 2048 * 2;  // 25.17 MB

  ushort* xb = (ushort*)d_out;  // bf16 x in d_out scratch (dead before final write)
  cvt2d<<<8192, 256, 0, stream>>>(xf, xb, 4096, 2048, 2048);

  if (ws_size >= SZ_QKV + SZ_ATTN + SZ_WQT) {
    // Tier A: un-sliced QKV gemm, attn in ws, final gemm direct to d_out.
    ushort* qkv   = (ushort*)ws;
    ushort* attnb = (ushort*)(ws + SZ_QKV);
    ushort* WT    = (ushort*)(ws + SZ_QKV + SZ_ATTN);
    cvt2dT<<<dim3(192, 64), dim3(32, 8), 0, stream>>>(Wqkvf, WT, 2048, 6144, NQKV);
    gemm_bt<ushort><<<dim3(32, 48), 256, 0, stream>>>(xb, WT, qkv, 4096, 6144, 2048, NQKV);
    flash_attn<<<dim3(32, 32), 256, 0, stream>>>(qkv, attnb);
    cvt2dT<<<dim3(64, 64), dim3(32, 8), 0, stream>>>(Woutf, WT, 2048, 2048, 2048);
    gemm_bt<float><<<dim3(32, 16), 256, 0, stream>>>(attnb, WT, outf, 4096, 2048, 2048, DMODEL);
  } else {
    // Tier B (ws >= 50.33 MB): sliced QKV, attn in d_out, memcpy back.
    ushort* qkv   = (ushort*)ws;
    float*  of    = (float*)ws;
    ushort* wbT   = (ushort*)d_out + (size_t)4096 * 2048;
    ushort* attnb = xb;
    for (int s = 0; s < 3; s++) {
      cvt2dT<<<dim3(64, 64), dim3(32, 8), 0, stream>>>(Wqkvf + s * 2048, wbT, 2048, 2048, NQKV);
      gemm_bt<ushort><<<dim3(32, 16), 256, 0, stream>>>(xb, wbT, qkv + s * 2048, 4096, 2048, 2048, NQKV);
    }
    flash_attn<<<dim3(32, 32), 256, 0, stream>>>(qkv, attnb);
    cvt2dT<<<dim3(64, 64), dim3(32, 8), 0, stream>>>(Woutf, wbT, 2048, 2048, 2048);
    gemm_bt<float><<<dim3(32, 16), 256, 0, stream>>>(attnb, wbT, of, 4096, 2048, 2048, DMODEL);
    hipMemcpyAsync(outf, of, (size_t)4096 * 2048 * 4, hipMemcpyDeviceToDevice, stream);
  }
}